// Round 11
// baseline (209.049 us; speedup 1.0000x reference)
//
#include <hip/hip_runtime.h>
#include <hip/hip_bf16.h>

// B=8, N=8192, S=2048, D1=128, D2=256, mlp=[256,128], in_ch=384. All fp32 I/O.
#define BATCH 8
#define NPTS  8192
#define SPTS  2048
#define D1C   128
#define D2C   256
#define C_IN  384
#define O0    256
#define O1    128
#define MROWS (BATCH * NPTS)   // 65536
#define NCHUNK 8
#define CHSZ   256             // staging chunk (scan grid.y)
#define NMIN   32              // 32 chunks of 64 points

typedef __attribute__((ext_vector_type(8))) short short8v;
typedef __attribute__((ext_vector_type(4))) float f32x4;

__device__ __forceinline__ unsigned short f2bf(float f) {
    union { float f; unsigned u; } v; v.f = f;
    unsigned u = v.u;
    return (unsigned short)((u + 0x7fffu + ((u >> 16) & 1u)) >> 16);  // RNE
}
__device__ __forceinline__ float bf2f(unsigned short h) {
    union { unsigned u; float f; } v; v.u = ((unsigned)h) << 16;
    return v.f;
}
__device__ __forceinline__ void gload_lds16(const void* g, void* l) {
    __builtin_amdgcn_global_load_lds(
        (const __attribute__((address_space(1))) void*)g,
        (__attribute__((address_space(3))) void*)l, 16, 0, 0);
}

// ---------------------------------------------------------------------------
// Pass 1: per-64-chunk MIN distance only. Inner loop = 5 d-calc + 1 fmin.
// grid (256 query-blocks, 8 staging-chunks); each staging chunk of 256 pts
// yields 4 minima (sub-chunks of 64).
// ---------------------------------------------------------------------------
__global__ __launch_bounds__(256, 8) void nn3_scan_min(
    const float* __restrict__ xyz1, const float* __restrict__ xyz2,
    float* __restrict__ candM)
{
    __shared__ float4 P[CHSZ];
    const int t  = threadIdx.x;
    const int qb = blockIdx.x;
    const int c  = blockIdx.y;
    const int b  = qb >> 5;

    {
        const float* src = xyz2 + ((size_t)b * SPTS + c * CHSZ) * 3;
        float px = src[t * 3 + 0];
        float py = src[t * 3 + 1];
        float pz = src[t * 3 + 2];
        P[t] = make_float4(px, py, pz, px * px + py * py + pz * pz);
    }
    __syncthreads();

    const int q = qb * 256 + t;
    const float* qp = xyz1 + (size_t)q * 3;
    const float qx = qp[0], qy = qp[1], qz = qp[2];
    const float qn = qx * qx + qy * qy + qz * qz;

    #pragma unroll
    for (int sub = 0; sub < 4; ++sub) {
        float m0 = 1e30f, m1 = 1e30f;
        #pragma unroll 8
        for (int s = sub * 64; s < sub * 64 + 64; s += 2) {
            float4 p0 = P[s];
            float4 p1 = P[s + 1];
            float da = (qn + p0.w) - 2.0f * (qx * p0.x + qy * p0.y + qz * p0.z);
            float db = (qn + p1.w) - 2.0f * (qx * p1.x + qy * p1.y + qz * p1.z);
            m0 = fminf(m0, da);
            m1 = fminf(m1, db);
        }
        candM[(size_t)(c * 4 + sub) * MROWS + q] = fminf(m0, m1);
    }
}

// ---------------------------------------------------------------------------
// Pass 2: select the 3 chunks with smallest minima (value, chunk-id asc
// tie-break via strict-< insertion in ascending chunk order). Covering
// argument: every true lex-(d,idx) top-3 member lies in one of these chunks.
// ---------------------------------------------------------------------------
__global__ __launch_bounds__(256) void nn3_chunksel(
    const float* __restrict__ candM, int* __restrict__ cid3)
{
    const int q = blockIdx.x * 256 + threadIdx.x;
    float d0 = 1e30f, d1 = 1e30f, d2 = 1e30f;
    int   i0 = 0,     i1 = 0,     i2 = 0;
    #pragma unroll
    for (int c = 0; c < NMIN; ++c) {
        float d = candM[(size_t)c * MROWS + q];
        bool c0 = d < d0, c1 = d < d1, c2 = d < d2;
        float t2 = __builtin_amdgcn_fmed3f(d, d1, d2);
        float t1 = __builtin_amdgcn_fmed3f(d, d0, d1);
        i2 = c1 ? i1 : (c2 ? c : i2);
        i1 = c0 ? i0 : (c1 ? c : i1);
        i0 = c0 ? c : i0;
        d2 = t2; d1 = t1; d0 = fminf(d, d0);
    }
    cid3[q * 3 + 0] = i0;
    cid3[q * 3 + 1] = i1;
    cid3[q * 3 + 2] = i2;
}

// ---------------------------------------------------------------------------
// Pass 3: fix-up. Stage the full batch (2048 pts, +s>>6 swizzle vs the
// stride-64 bank pathology), rescan the 3 selected chunks in ASCENDING chunk
// order with the verbatim r7 tracker -> exact top-3 (d,idx) -> weights.
// ---------------------------------------------------------------------------
__global__ __launch_bounds__(256) void nn3_fixup(
    const float* __restrict__ xyz1, const float* __restrict__ xyz2,
    const int* __restrict__ cid3,
    int* __restrict__ idx3, float* __restrict__ wgt3)
{
    __shared__ float4 P[SPTS + SPTS / 64];   // swizzled: P[s + (s>>6)]
    const int t = threadIdx.x;
    const int b = blockIdx.x >> 5;

    {
        const float* x2 = xyz2 + (size_t)b * SPTS * 3;
        for (int s = t; s < SPTS; s += 256) {
            float px = x2[s * 3 + 0];
            float py = x2[s * 3 + 1];
            float pz = x2[s * 3 + 2];
            P[s + (s >> 6)] = make_float4(px, py, pz, px * px + py * py + pz * pz);
        }
    }
    __syncthreads();

    const int q = blockIdx.x * 256 + t;
    const float* qp = xyz1 + (size_t)q * 3;
    const float qx = qp[0], qy = qp[1], qz = qp[2];
    const float qn = qx * qx + qy * qy + qz * qz;

    const int ca = cid3[q * 3 + 0];
    const int cb = cid3[q * 3 + 1];
    const int cc = cid3[q * 3 + 2];
    const int lo = min(ca, min(cb, cc));
    const int hi = max(ca, max(cb, cc));
    const int md = ca + cb + cc - lo - hi;
    const int chunks[3] = {lo, md, hi};

    float d0 = 1e30f, d1 = 1e30f, d2 = 1e30f;
    int   i0 = 0,     i1 = 0,     i2 = 0;

    #pragma unroll
    for (int k = 0; k < 3; ++k) {
        const int cid   = chunks[k];        // static k -> register
        const int base  = cid * 65;         // swizzled base
        const int gbase = cid * 64;
        #pragma unroll 4
        for (int s = 0; s < 64; ++s) {
            float4 p = P[base + s];
            float dot = qx * p.x + qy * p.y + qz * p.z;
            float d = (qn + p.w) - 2.0f * dot;   // verbatim reference formula
            bool c0 = d < d0, c1 = d < d1, c2 = d < d2;
            int gi = gbase + s;
            float t2 = __builtin_amdgcn_fmed3f(d, d1, d2);
            float t1 = __builtin_amdgcn_fmed3f(d, d0, d1);
            i2 = c1 ? i1 : (c2 ? gi : i2);
            i1 = c0 ? i0 : (c1 ? gi : i1);
            i0 = c0 ? gi : i0;
            d2 = t2; d1 = t1; d0 = fminf(d, d0);
        }
    }

    float wa = 1.0f / (d0 + 1e-8f);
    float wb = 1.0f / (d1 + 1e-8f);
    float wc = 1.0f / (d2 + 1e-8f);
    float inv = 1.0f / (wa + wb + wc);
    wa *= inv; wb *= inv; wc *= inv;

    idx3[q * 3 + 0] = i0;
    idx3[q * 3 + 1] = i1;
    idx3[q * 3 + 2] = i2;
    wgt3[q * 3 + 0] = wa;
    wgt3[q * 3 + 1] = wb;
    wgt3[q * 3 + 2] = wc;
}

// ---------------------------------------------------------------------------
// fp32 -> bf16 weight conversion. UNCHANGED.
// ---------------------------------------------------------------------------
__global__ __launch_bounds__(256) void cvt_f32_bf16(
    const float* __restrict__ src, unsigned short* __restrict__ dst)
{
    int i = blockIdx.x * 256 + threadIdx.x;
    float4 v = ((const float4*)src)[i];
    ushort4 o;
    o.x = f2bf(v.x); o.y = f2bf(v.y); o.z = f2bf(v.z); o.w = f2bf(v.w);
    ((ushort4*)dst)[i] = o;
}

// ---------------------------------------------------------------------------
// Interpolation gather with batch-per-XCD block swizzle (proven r7/r9).
// ---------------------------------------------------------------------------
__global__ __launch_bounds__(256) void interp_kernel(
    const float* __restrict__ points2,
    const int* __restrict__ idx3, const float* __restrict__ wgt3,
    unsigned short* __restrict__ xI)
{
    const int w    = threadIdx.x >> 6;
    const int lane = threadIdx.x & 63;
    const int blk   = blockIdx.x;              // 0..16383
    const int xcd   = blk & 7;
    const int local = blk >> 3;                // 0..2047
    const int m     = (xcd * 2048 + local) * 4 + w;   // batch = m>>13 = xcd
    const int b     = xcd;

    const float* p2b = points2 + (size_t)b * SPTS * D2C;
    const int  gi0 = idx3[m * 3 + 0];
    const int  gi1 = idx3[m * 3 + 1];
    const int  gi2 = idx3[m * 3 + 2];
    const float w0 = wgt3[m * 3 + 0];
    const float w1 = wgt3[m * 3 + 1];
    const float w2 = wgt3[m * 3 + 2];

    float4 a  = *(const float4*)(p2b + (size_t)gi0 * D2C + lane * 4);
    float4 bb = *(const float4*)(p2b + (size_t)gi1 * D2C + lane * 4);
    float4 c  = *(const float4*)(p2b + (size_t)gi2 * D2C + lane * 4);

    ushort4 o;
    o.x = f2bf(w0 * a.x + w1 * bb.x + w2 * c.x);
    o.y = f2bf(w0 * a.y + w1 * bb.y + w2 * c.y);
    o.z = f2bf(w0 * a.z + w1 * bb.z + w2 * c.z);
    o.w = f2bf(w0 * a.w + w1 * bb.w + w2 * c.w);
    *(ushort4*)(xI + (size_t)m * D2C + lane * 4) = o;
}

// ---------------------------------------------------------------------------
// GEMM0 (MFMA bf16), double-buffered (r9, best). A=[points1|xI], B=w0bf.
// ---------------------------------------------------------------------------
__global__ __launch_bounds__(512, 4) void gemm0_mfma(
    const float* __restrict__ points1, const unsigned short* __restrict__ xI,
    const unsigned short* __restrict__ w0bf, const float* __restrict__ b0,
    unsigned short* __restrict__ y0bf,
    float* __restrict__ sum0, float* __restrict__ sq0)
{
    __shared__ __align__(16) unsigned short As[2][128 * 32];   // 16 KB
    __shared__ __align__(16) unsigned short Bs[2][256 * 32];   // 32 KB

    const int t    = threadIdx.x;
    const int lane = t & 63;
    const int w    = t >> 6;
    const int wm   = w >> 2;
    const int wn   = w & 3;
    const int rowBase = blockIdx.x * 128;

    const int r      = t >> 2;                      // 0..127
    const int ks_log = (t & 3) ^ ((t >> 3) & 3);    // logical k-slot

    const float* p1row = points1 + (size_t)(rowBase + r) * D1C;
    const unsigned short* xrow = xI + (size_t)(rowBase + r) * D2C + ks_log * 8;
    const unsigned short* gB0 = w0bf + (size_t)r * C_IN + ks_log * 8;
    const unsigned short* gB1 = w0bf + (size_t)(128 + r) * C_IN + ks_log * 8;

    const int rp = (lane & 15) * 64 + (((lane >> 4) ^ ((lane >> 1) & 3)) * 16);

    f32x4 acc[4][4] = {};

    auto stage = [&](int buf, int kt) {
        gload_lds16(gB0 + kt * 32, (char*)Bs[buf] + w * 1024);
        gload_lds16(gB1 + kt * 32, (char*)Bs[buf] + 8192 + w * 1024);
        if (kt < 4) {
            const int k = kt * 32 + ks_log * 8;
            float4 f0 = *(const float4*)(p1row + k);
            float4 f1 = *(const float4*)(p1row + k + 4);
            short8v av;
            av[0] = (short)f2bf(f0.x); av[1] = (short)f2bf(f0.y);
            av[2] = (short)f2bf(f0.z); av[3] = (short)f2bf(f0.w);
            av[4] = (short)f2bf(f1.x); av[5] = (short)f2bf(f1.y);
            av[6] = (short)f2bf(f1.z); av[7] = (short)f2bf(f1.w);
            *(short8v*)(As[buf] + t * 8) = av;
        } else {
            gload_lds16(xrow + (kt - 4) * 32, (char*)As[buf] + w * 1024);
        }
    };

    auto compute = [&](int buf) {
        const char* aB = (const char*)As[buf] + (wm * 64) * 64 + rp;
        const char* bB = (const char*)Bs[buf] + (wn * 64) * 64 + rp;
        short8v a[4], bv[4];
        #pragma unroll
        for (int m = 0; m < 4; ++m) a[m]  = *(const short8v*)(aB + m * 1024);
        #pragma unroll
        for (int n = 0; n < 4; ++n) bv[n] = *(const short8v*)(bB + n * 1024);
        #pragma unroll
        for (int m = 0; m < 4; ++m)
            #pragma unroll
            for (int n = 0; n < 4; ++n)
                acc[m][n] = __builtin_amdgcn_mfma_f32_16x16x32_bf16(
                    a[m], bv[n], acc[m][n], 0, 0, 0);
    };

    stage(0, 0);
    __syncthreads();
    #pragma unroll
    for (int kt = 0; kt < C_IN / 32; ++kt) {
        if (kt + 1 < C_IN / 32) stage((kt + 1) & 1, kt + 1);
        compute(kt & 1);
        __syncthreads();
    }

    const int colw = wn * 64 + (lane & 15);
    const int rowE = rowBase + wm * 64 + ((lane >> 4) * 4);
    float bias[4];
    #pragma unroll
    for (int n = 0; n < 4; ++n) bias[n] = b0[colw + n * 16];

    float cs[4] = {0.f, 0.f, 0.f, 0.f}, cq[4] = {0.f, 0.f, 0.f, 0.f};
    #pragma unroll
    for (int m = 0; m < 4; ++m)
        #pragma unroll
        for (int n = 0; n < 4; ++n)
            #pragma unroll
            for (int j = 0; j < 4; ++j) {
                float v = acc[m][n][j] + bias[n];
                y0bf[(size_t)(rowE + m * 16 + j) * O0 + colw + n * 16] = f2bf(v);
                cs[n] += v; cq[n] += v * v;
            }

    #pragma unroll
    for (int n = 0; n < 4; ++n) {
        float s = cs[n], qv = cq[n];
        s  += __shfl_xor(s, 16);  s  += __shfl_xor(s, 32);
        qv += __shfl_xor(qv, 16); qv += __shfl_xor(qv, 32);
        if (lane < 16) {
            atomicAdd(&sum0[colw + n * 16], s);
            atomicAdd(&sq0[colw + n * 16], qv);
        }
    }
}

// ---------------------------------------------------------------------------
// stats: scale = g * rsqrt(var+eps), shift = beta - mean*scale. UNCHANGED.
// ---------------------------------------------------------------------------
__global__ void stats_kernel(const float* __restrict__ sum, const float* __restrict__ sq,
                             const float* __restrict__ g, const float* __restrict__ beta,
                             float* __restrict__ scale, float* __restrict__ shift,
                             int C, float invM)
{
    int c = blockIdx.x * blockDim.x + threadIdx.x;
    if (c < C) {
        float mean = sum[c] * invM;
        float var  = sq[c] * invM - mean * mean;
        float s = g[c] * rsqrtf(var + 1e-5f);
        scale[c] = s;
        shift[c] = beta[c] - mean * s;
    }
}

// ---------------------------------------------------------------------------
// GEMM1 (MFMA bf16), dbuf, fused BN0+ReLU on A; y1 bf16 + BN1 stats. (r9)
// ---------------------------------------------------------------------------
__global__ __launch_bounds__(256, 2) void gemm1_mfma(
    const unsigned short* __restrict__ x1, const unsigned short* __restrict__ w1bf,
    const float* __restrict__ scale0, const float* __restrict__ shift0,
    const float* __restrict__ b1, unsigned short* __restrict__ y1bf,
    float* __restrict__ sum1, float* __restrict__ sq1)
{
    __shared__ __align__(16) unsigned short As[2][128 * 32];
    __shared__ __align__(16) unsigned short Bs[2][128 * 32];
    __shared__ float sc[O0], sh[O0];

    const int t    = threadIdx.x;
    const int lane = t & 63;
    const int w    = t >> 6;
    const int wm   = w >> 1, wn = w & 1;
    const int rowBase = blockIdx.x * 128;

    sc[t] = scale0[t];
    sh[t] = shift0[t];
    __syncthreads();

    const int r      = t >> 2;
    const int kl     = t & 3;
    const int kp     = kl ^ ((r >> 1) & 3);
    const int ks_log = kl ^ ((r >> 1) & 3);

    const unsigned short* gA0 = x1 + (size_t)(rowBase + r) * O0 + kl * 8;
    const unsigned short* gA1 = x1 + (size_t)(rowBase + 64 + r) * O0 + kl * 8;
    const unsigned short* gB0 = w1bf + (size_t)r * O0 + ks_log * 8;
    const unsigned short* gB1 = w1bf + (size_t)(64 + r) * O0 + ks_log * 8;

    const int rp = (lane & 15) * 64 + (((lane >> 4) ^ ((lane >> 1) & 3)) * 16);

    f32x4 acc[4][4] = {};

    auto stage = [&](int buf, int kt) {
        gload_lds16(gB0 + kt * 32, (char*)Bs[buf] + w * 1024);
        gload_lds16(gB1 + kt * 32, (char*)Bs[buf] + 4096 + w * 1024);

        const int ch = kt * 32 + kl * 8;
        float4 s0v = *(const float4*)(sc + ch);
        float4 s1v = *(const float4*)(sc + ch + 4);
        float4 h0v = *(const float4*)(sh + ch);
        float4 h1v = *(const float4*)(sh + ch + 4);
        short8v v0 = *(const short8v*)(gA0 + kt * 32);
        short8v v1 = *(const short8v*)(gA1 + kt * 32);
        short8v o0, o1;
        o0[0] = (short)f2bf(fmaxf(0.f, bf2f((unsigned short)v0[0]) * s0v.x + h0v.x));
        o0[1] = (short)f2bf(fmaxf(0.f, bf2f((unsigned short)v0[1]) * s0v.y + h0v.y));
        o0[2] = (short)f2bf(fmaxf(0.f, bf2f((unsigned short)v0[2]) * s0v.z + h0v.z));
        o0[3] = (short)f2bf(fmaxf(0.f, bf2f((unsigned short)v0[3]) * s0v.w + h0v.w));
        o0[4] = (short)f2bf(fmaxf(0.f, bf2f((unsigned short)v0[4]) * s1v.x + h1v.x));
        o0[5] = (short)f2bf(fmaxf(0.f, bf2f((unsigned short)v0[5]) * s1v.y + h1v.y));
        o0[6] = (short)f2bf(fmaxf(0.f, bf2f((unsigned short)v0[6]) * s1v.z + h1v.z));
        o0[7] = (short)f2bf(fmaxf(0.f, bf2f((unsigned short)v0[7]) * s1v.w + h1v.w));
        o1[0] = (short)f2bf(fmaxf(0.f, bf2f((unsigned short)v1[0]) * s0v.x + h0v.x));
        o1[1] = (short)f2bf(fmaxf(0.f, bf2f((unsigned short)v1[1]) * s0v.y + h0v.y));
        o1[2] = (short)f2bf(fmaxf(0.f, bf2f((unsigned short)v1[2]) * s0v.z + h0v.z));
        o1[3] = (short)f2bf(fmaxf(0.f, bf2f((unsigned short)v1[3]) * s0v.w + h0v.w));
        o1[4] = (short)f2bf(fmaxf(0.f, bf2f((unsigned short)v1[4]) * s1v.x + h1v.x));
        o1[5] = (short)f2bf(fmaxf(0.f, bf2f((unsigned short)v1[5]) * s1v.y + h1v.y));
        o1[6] = (short)f2bf(fmaxf(0.f, bf2f((unsigned short)v1[6]) * s1v.z + h1v.z));
        o1[7] = (short)f2bf(fmaxf(0.f, bf2f((unsigned short)v1[7]) * s1v.w + h1v.w));
        *(short8v*)(As[buf] + r * 32 + kp * 8) = o0;
        *(short8v*)(As[buf] + (64 + r) * 32 + kp * 8) = o1;
    };

    auto compute = [&](int buf) {
        const char* aB = (const char*)As[buf] + (wm * 64) * 64 + rp;
        const char* bB = (const char*)Bs[buf] + (wn * 64) * 64 + rp;
        short8v a[4], bv[4];
        #pragma unroll
        for (int m = 0; m < 4; ++m) a[m]  = *(const short8v*)(aB + m * 1024);
        #pragma unroll
        for (int n = 0; n < 4; ++n) bv[n] = *(const short8v*)(bB + n * 1024);
        #pragma unroll
        for (int m = 0; m < 4; ++m)
            #pragma unroll
            for (int n = 0; n < 4; ++n)
                acc[m][n] = __builtin_amdgcn_mfma_f32_16x16x32_bf16(
                    a[m], bv[n], acc[m][n], 0, 0, 0);
    };

    stage(0, 0);
    __syncthreads();
    #pragma unroll
    for (int kt = 0; kt < O0 / 32; ++kt) {
        if (kt + 1 < O0 / 32) stage((kt + 1) & 1, kt + 1);
        compute(kt & 1);
        __syncthreads();
    }

    const int colw = wn * 64 + (lane & 15);
    const int rowE = rowBase + wm * 64 + ((lane >> 4) * 4);
    float bias[4];
    #pragma unroll
    for (int n = 0; n < 4; ++n) bias[n] = b1[colw + n * 16];

    float cs[4] = {0.f, 0.f, 0.f, 0.f}, cq[4] = {0.f, 0.f, 0.f, 0.f};
    #pragma unroll
    for (int m = 0; m < 4; ++m)
        #pragma unroll
        for (int n = 0; n < 4; ++n)
            #pragma unroll
            for (int j = 0; j < 4; ++j) {
                float v = acc[m][n][j] + bias[n];
                y1bf[(size_t)(rowE + m * 16 + j) * O1 + colw + n * 16] = f2bf(v);
                cs[n] += v; cq[n] += v * v;
            }

    #pragma unroll
    for (int n = 0; n < 4; ++n) {
        float s = cs[n], qv = cq[n];
        s  += __shfl_xor(s, 16);  s  += __shfl_xor(s, 32);
        qv += __shfl_xor(qv, 16); qv += __shfl_xor(qv, 32);
        if (lane < 16) {
            atomicAdd(&sum1[colw + n * 16], s);
            atomicAdd(&sq1[colw + n * 16], qv);
        }
    }
}

// ---------------------------------------------------------------------------
// Final BN1 + ReLU: reads bf16 y1, writes fp32 d_out. UNCHANGED.
// ---------------------------------------------------------------------------
__global__ __launch_bounds__(256) void bn_relu_out(
    const unsigned short* __restrict__ y1bf, float* __restrict__ out,
    const float* __restrict__ scale, const float* __restrict__ shift)
{
    int i = blockIdx.x * 256 + threadIdx.x;       // chunk of 8 elems
    short8v v = ((const short8v*)y1bf)[i];
    int c = (i * 8) & (O1 - 1);
    float4 sa = *(const float4*)(scale + c);
    float4 sb = *(const float4*)(scale + c + 4);
    float4 ha = *(const float4*)(shift + c);
    float4 hb = *(const float4*)(shift + c + 4);
    float4 o0, o1;
    o0.x = fmaxf(0.f, bf2f((unsigned short)v[0]) * sa.x + ha.x);
    o0.y = fmaxf(0.f, bf2f((unsigned short)v[1]) * sa.y + ha.y);
    o0.z = fmaxf(0.f, bf2f((unsigned short)v[2]) * sa.z + ha.z);
    o0.w = fmaxf(0.f, bf2f((unsigned short)v[3]) * sa.w + ha.w);
    o1.x = fmaxf(0.f, bf2f((unsigned short)v[4]) * sb.x + hb.x);
    o1.y = fmaxf(0.f, bf2f((unsigned short)v[5]) * sb.y + hb.y);
    o1.z = fmaxf(0.f, bf2f((unsigned short)v[6]) * sb.z + hb.z);
    o1.w = fmaxf(0.f, bf2f((unsigned short)v[7]) * sb.w + hb.w);
    ((float4*)out)[i * 2 + 0] = o0;
    ((float4*)out)[i * 2 + 1] = o1;
}

// ---------------------------------------------------------------------------
// ws layout (float offsets), peak 16844288 f = 67.4 MB:
//   0..1536        stats
//   1536..50688    w0bf
//   50688..67072   w1bf
//   OVERLAY @67072 (all dead before gemm0 writes y0bf here):
//     candM @132608..2229760   (32 x M f32; dead after chunksel)
//     cid3  @2229760..2426368  (3M ints; dead after fixup)
//     idx3  @2426368..2622976  (dead after interp)
//     wgt3  @2622976..2819584  (dead after interp)
//   y0bf @67072..8455680       (written by gemm0)
//   xI   @8455680..16844288    (dead after gemm0; y1bf overlays it)
//   y1bf @8455680..12649984    (written by gemm1)
// ---------------------------------------------------------------------------
extern "C" void kernel_launch(void* const* d_in, const int* in_sizes, int n_in,
                              void* d_out, int out_size, void* d_ws, size_t ws_size,
                              hipStream_t stream)
{
    const float* xyz1    = (const float*)d_in[0];
    const float* xyz2    = (const float*)d_in[1];
    const float* points1 = (const float*)d_in[2];
    const float* points2 = (const float*)d_in[3];
    const float* w0      = (const float*)d_in[4];
    const float* b0      = (const float*)d_in[5];
    const float* g0      = (const float*)d_in[6];
    const float* beta0   = (const float*)d_in[7];
    const float* w1      = (const float*)d_in[8];
    const float* b1      = (const float*)d_in[9];
    const float* g1      = (const float*)d_in[10];
    const float* beta1   = (const float*)d_in[11];

    float* wsf = (float*)d_ws;
    float* sum0   = wsf;
    float* sq0    = wsf + 256;
    float* sum1   = wsf + 512;
    float* sq1    = wsf + 640;
    float* scale0 = wsf + 768;
    float* shift0 = wsf + 1024;
    float* scale1 = wsf + 1280;
    float* shift1 = wsf + 1408;
    unsigned short* w0bf = (unsigned short*)(wsf + 1536);
    unsigned short* w1bf = (unsigned short*)(wsf + 50688);
    float*  candM = wsf + 132608;
    int*    cid3  = (int*)(wsf + 2229760);
    int*    idx3  = (int*)(wsf + 2426368);
    float*  wgt3  = wsf + 2622976;
    unsigned short* y0bf = (unsigned short*)(wsf + 67072);
    unsigned short* xI   = (unsigned short*)(wsf + 8455680);
    unsigned short* y1bf = (unsigned short*)(wsf + 8455680);

    hipMemsetAsync(d_ws, 0, 768 * sizeof(float), stream);

    cvt_f32_bf16<<<(O0 * C_IN / 4) / 256, 256, 0, stream>>>(w0, w0bf);
    cvt_f32_bf16<<<(O1 * O0 / 4) / 256, 256, 0, stream>>>(w1, w1bf);

    nn3_scan_min<<<dim3(MROWS / 256, NCHUNK), 256, 0, stream>>>(xyz1, xyz2, candM);
    nn3_chunksel<<<MROWS / 256, 256, 0, stream>>>(candM, cid3);
    nn3_fixup<<<MROWS / 256, 256, 0, stream>>>(xyz1, xyz2, cid3, idx3, wgt3);

    interp_kernel<<<MROWS / 4, 256, 0, stream>>>(points2, idx3, wgt3, xI);

    gemm0_mfma<<<MROWS / 128, 512, 0, stream>>>(
        points1, xI, w0bf, b0, y0bf, sum0, sq0);

    stats_kernel<<<1, 256, 0, stream>>>(sum0, sq0, g0, beta0, scale0, shift0,
                                        O0, 1.0f / MROWS);

    gemm1_mfma<<<MROWS / 128, 256, 0, stream>>>(
        y0bf, w1bf, scale0, shift0, b1, y1bf, sum1, sq1);

    stats_kernel<<<1, 128, 0, stream>>>(sum1, sq1, g1, beta1, scale1, shift1,
                                        O1, 1.0f / MROWS);

    bn_relu_out<<<(MROWS * O1 / 8) / 256, 256, 0, stream>>>(
        y1bf, (float*)d_out, scale1, shift1);
}

// Round 12
// 186.682 us; speedup vs baseline: 1.1198x; 1.1198x over previous
//
#include <hip/hip_runtime.h>
#include <hip/hip_bf16.h>

// B=8, N=8192, S=2048, D1=128, D2=256, mlp=[256,128], in_ch=384. All fp32 I/O.
#define BATCH 8
#define NPTS  8192
#define SPTS  2048
#define D1C   128
#define D2C   256
#define C_IN  384
#define O0    256
#define O1    128
#define MROWS (BATCH * NPTS)   // 65536
#define NCHUNK 8
#define CHSZ   256             // SPTS / NCHUNK

typedef __attribute__((ext_vector_type(8))) short short8v;
typedef __attribute__((ext_vector_type(4))) float f32x4;
typedef unsigned long long u64;

#define PKINIT 0x7FE0000000000000ULL   // huge positive double > any packed value

__device__ __forceinline__ unsigned short f2bf(float f) {
    union { float f; unsigned u; } v; v.f = f;
    unsigned u = v.u;
    return (unsigned short)((u + 0x7fffu + ((u >> 16) & 1u)) >> 16);  // RNE
}
__device__ __forceinline__ float bf2f(unsigned short h) {
    union { unsigned u; float f; } v; v.u = ((unsigned)h) << 16;
    return v.f;
}
__device__ __forceinline__ void gload_lds16(const void* g, void* l) {
    __builtin_amdgcn_global_load_lds(
        (const __attribute__((address_space(1))) void*)g,
        (__attribute__((address_space(3))) void*)l, 16, 0, 0);
}

// d (f32) + idx -> positive finite double whose numeric order == lex(d, idx).
// u = sortable-uint map of d (exact, handles negatives); pk = (u<<31)|idx:
// bit63=0, exp field can't be all-ones for |d| < 1e38 -> valid positive double.
__device__ __forceinline__ double pack_di(float d, int idx) {
    union { float f; unsigned u; } b; b.f = d;
    unsigned db = b.u;
    unsigned u  = db ^ ((unsigned)((int)db >> 31) | 0x80000000u);
    union { u64 q; double x; } p;
    p.q = ((u64)u << 31) | (unsigned)idx;
    return p.x;
}
__device__ __forceinline__ void unpack_di(double x, float* d, int* idx) {
    union { double x; u64 q; } p; p.x = x;
    unsigned u = (unsigned)(p.q >> 31);
    unsigned db = (u & 0x80000000u) ? (u ^ 0x80000000u) : ~u;
    union { unsigned u; float f; } b; b.u = db;
    *d = b.f;
    *idx = (int)(p.q & 0x7FFu);
}
// sorted-insert x into (p0<=p1<=p2), keeping 3 smallest. 5 f64 min/max ops.
__device__ __forceinline__ void ins3(double& p0, double& p1, double& p2, double x) {
    double l0 = fmax(p0, x);
    p0 = fmin(p0, x);
    double l1 = fmax(p1, l0);
    p1 = fmin(p1, l0);
    p2 = fmin(p2, l1);
}

// ---------------------------------------------------------------------------
// Kernel 1a: chunked 3-NN scan — r7 structure, packed-f64 top-3 tracker.
// Inner loop: 5 d-calc + ~6 pack + 5 f64 min/max. No cmp/cndmask chains.
// ---------------------------------------------------------------------------
__global__ __launch_bounds__(256, 8) void nn3_scan(
    const float* __restrict__ xyz1, const float* __restrict__ xyz2,
    u64* __restrict__ candP)
{
    __shared__ float4 P[CHSZ];
    const int t  = threadIdx.x;
    const int qb = blockIdx.x;
    const int c  = blockIdx.y;
    const int b  = qb >> 5;

    {
        const float* src = xyz2 + ((size_t)b * SPTS + c * CHSZ) * 3;
        float px = src[t * 3 + 0];
        float py = src[t * 3 + 1];
        float pz = src[t * 3 + 2];
        P[t] = make_float4(px, py, pz, px * px + py * py + pz * pz);
    }
    __syncthreads();

    const int q = qb * 256 + t;
    const float* qp = xyz1 + (size_t)q * 3;
    const float qx = qp[0], qy = qp[1], qz = qp[2];
    const float qn = qx * qx + qy * qy + qz * qz;

    union { u64 q; double x; } init; init.q = PKINIT;
    double p0 = init.x, p1 = init.x, p2 = init.x;
    const int gbase = c * CHSZ;

    #pragma unroll 4
    for (int s = 0; s < CHSZ; ++s) {
        float4 p = P[s];
        float dot = qx * p.x + qy * p.y + qz * p.z;
        float d = (qn + p.w) - 2.0f * dot;      // verbatim reference formula
        ins3(p0, p1, p2, pack_di(d, gbase + s));
    }

    union { double x; u64 q; } o0, o1, o2;
    o0.x = p0; o1.x = p1; o2.x = p2;
    const size_t base = (size_t)c * (MROWS * 3) + (size_t)q * 3;
    candP[base + 0] = o0.q;
    candP[base + 1] = o1.q;
    candP[base + 2] = o2.q;
}

// ---------------------------------------------------------------------------
// Kernel 1b: merge 8 chunk-candidates (packed) -> top-3 -> idx + weights.
// Order-free: packed values form a total order (ties impossible).
// ---------------------------------------------------------------------------
__global__ __launch_bounds__(256) void nn3_merge(
    const u64* __restrict__ candP,
    int* __restrict__ idx3, float* __restrict__ wgt3)
{
    const int q = blockIdx.x * 256 + threadIdx.x;

    union { u64 q; double x; } init; init.q = PKINIT;
    double p0 = init.x, p1 = init.x, p2 = init.x;

    #pragma unroll
    for (int c = 0; c < NCHUNK; ++c) {
        const size_t base = (size_t)c * (MROWS * 3) + (size_t)q * 3;
        #pragma unroll
        for (int j = 0; j < 3; ++j) {
            union { u64 q; double x; } v; v.q = candP[base + j];
            ins3(p0, p1, p2, v.x);
        }
    }

    float d0, d1, d2; int i0, i1, i2;
    unpack_di(p0, &d0, &i0);
    unpack_di(p1, &d1, &i1);
    unpack_di(p2, &d2, &i2);

    float wa = 1.0f / (d0 + 1e-8f);
    float wb = 1.0f / (d1 + 1e-8f);
    float wc = 1.0f / (d2 + 1e-8f);
    float inv = 1.0f / (wa + wb + wc);
    wa *= inv; wb *= inv; wc *= inv;

    idx3[q * 3 + 0] = i0;
    idx3[q * 3 + 1] = i1;
    idx3[q * 3 + 2] = i2;
    wgt3[q * 3 + 0] = wa;
    wgt3[q * 3 + 1] = wb;
    wgt3[q * 3 + 2] = wc;
}

// ---------------------------------------------------------------------------
// fused fp32 -> bf16 conversion for both weight matrices (1 launch).
// ---------------------------------------------------------------------------
__global__ __launch_bounds__(256) void cvt_weights(
    const float* __restrict__ w0, const float* __restrict__ w1,
    unsigned short* __restrict__ w0bf, unsigned short* __restrict__ w1bf)
{
    int i = blockIdx.x * 256 + threadIdx.x;
    const int n0 = O0 * C_IN / 4;      // 24576 float4s in w0
    const float* src; unsigned short* dst; int j;
    if (i < n0) { src = w0; dst = w0bf; j = i; }
    else        { src = w1; dst = w1bf; j = i - n0; }
    float4 v = ((const float4*)src)[j];
    ushort4 o;
    o.x = f2bf(v.x); o.y = f2bf(v.y); o.z = f2bf(v.z); o.w = f2bf(v.w);
    ((ushort4*)dst)[j] = o;
}

// ---------------------------------------------------------------------------
// Interpolation gather with batch-per-XCD block swizzle (proven r7/r9).
// ---------------------------------------------------------------------------
__global__ __launch_bounds__(256) void interp_kernel(
    const float* __restrict__ points2,
    const int* __restrict__ idx3, const float* __restrict__ wgt3,
    unsigned short* __restrict__ xI)
{
    const int w    = threadIdx.x >> 6;
    const int lane = threadIdx.x & 63;
    const int blk   = blockIdx.x;              // 0..16383
    const int xcd   = blk & 7;
    const int local = blk >> 3;                // 0..2047
    const int m     = (xcd * 2048 + local) * 4 + w;   // batch = m>>13 = xcd
    const int b     = xcd;

    const float* p2b = points2 + (size_t)b * SPTS * D2C;
    const int  gi0 = idx3[m * 3 + 0];
    const int  gi1 = idx3[m * 3 + 1];
    const int  gi2 = idx3[m * 3 + 2];
    const float w0 = wgt3[m * 3 + 0];
    const float w1 = wgt3[m * 3 + 1];
    const float w2 = wgt3[m * 3 + 2];

    float4 a  = *(const float4*)(p2b + (size_t)gi0 * D2C + lane * 4);
    float4 bb = *(const float4*)(p2b + (size_t)gi1 * D2C + lane * 4);
    float4 c  = *(const float4*)(p2b + (size_t)gi2 * D2C + lane * 4);

    ushort4 o;
    o.x = f2bf(w0 * a.x + w1 * bb.x + w2 * c.x);
    o.y = f2bf(w0 * a.y + w1 * bb.y + w2 * c.y);
    o.z = f2bf(w0 * a.z + w1 * bb.z + w2 * c.z);
    o.w = f2bf(w0 * a.w + w1 * bb.w + w2 * c.w);
    *(ushort4*)(xI + (size_t)m * D2C + lane * 4) = o;
}

// ---------------------------------------------------------------------------
// GEMM0 (MFMA bf16), double-buffered (r9). A=[points1|xI], B=w0bf.
// ---------------------------------------------------------------------------
__global__ __launch_bounds__(512, 4) void gemm0_mfma(
    const float* __restrict__ points1, const unsigned short* __restrict__ xI,
    const unsigned short* __restrict__ w0bf, const float* __restrict__ b0,
    unsigned short* __restrict__ y0bf,
    float* __restrict__ sum0, float* __restrict__ sq0)
{
    __shared__ __align__(16) unsigned short As[2][128 * 32];   // 16 KB
    __shared__ __align__(16) unsigned short Bs[2][256 * 32];   // 32 KB

    const int t    = threadIdx.x;
    const int lane = t & 63;
    const int w    = t >> 6;
    const int wm   = w >> 2;
    const int wn   = w & 3;
    const int rowBase = blockIdx.x * 128;

    const int r      = t >> 2;                      // 0..127
    const int ks_log = (t & 3) ^ ((t >> 3) & 3);    // logical k-slot

    const float* p1row = points1 + (size_t)(rowBase + r) * D1C;
    const unsigned short* xrow = xI + (size_t)(rowBase + r) * D2C + ks_log * 8;
    const unsigned short* gB0 = w0bf + (size_t)r * C_IN + ks_log * 8;
    const unsigned short* gB1 = w0bf + (size_t)(128 + r) * C_IN + ks_log * 8;

    const int rp = (lane & 15) * 64 + (((lane >> 4) ^ ((lane >> 1) & 3)) * 16);

    f32x4 acc[4][4] = {};

    auto stage = [&](int buf, int kt) {
        gload_lds16(gB0 + kt * 32, (char*)Bs[buf] + w * 1024);
        gload_lds16(gB1 + kt * 32, (char*)Bs[buf] + 8192 + w * 1024);
        if (kt < 4) {
            const int k = kt * 32 + ks_log * 8;
            float4 f0 = *(const float4*)(p1row + k);
            float4 f1 = *(const float4*)(p1row + k + 4);
            short8v av;
            av[0] = (short)f2bf(f0.x); av[1] = (short)f2bf(f0.y);
            av[2] = (short)f2bf(f0.z); av[3] = (short)f2bf(f0.w);
            av[4] = (short)f2bf(f1.x); av[5] = (short)f2bf(f1.y);
            av[6] = (short)f2bf(f1.z); av[7] = (short)f2bf(f1.w);
            *(short8v*)(As[buf] + t * 8) = av;
        } else {
            gload_lds16(xrow + (kt - 4) * 32, (char*)As[buf] + w * 1024);
        }
    };

    auto compute = [&](int buf) {
        const char* aB = (const char*)As[buf] + (wm * 64) * 64 + rp;
        const char* bB = (const char*)Bs[buf] + (wn * 64) * 64 + rp;
        short8v a[4], bv[4];
        #pragma unroll
        for (int m = 0; m < 4; ++m) a[m]  = *(const short8v*)(aB + m * 1024);
        #pragma unroll
        for (int n = 0; n < 4; ++n) bv[n] = *(const short8v*)(bB + n * 1024);
        #pragma unroll
        for (int m = 0; m < 4; ++m)
            #pragma unroll
            for (int n = 0; n < 4; ++n)
                acc[m][n] = __builtin_amdgcn_mfma_f32_16x16x32_bf16(
                    a[m], bv[n], acc[m][n], 0, 0, 0);
    };

    stage(0, 0);
    __syncthreads();
    #pragma unroll
    for (int kt = 0; kt < C_IN / 32; ++kt) {
        if (kt + 1 < C_IN / 32) stage((kt + 1) & 1, kt + 1);
        compute(kt & 1);
        __syncthreads();
    }

    const int colw = wn * 64 + (lane & 15);
    const int rowE = rowBase + wm * 64 + ((lane >> 4) * 4);
    float bias[4];
    #pragma unroll
    for (int n = 0; n < 4; ++n) bias[n] = b0[colw + n * 16];

    float cs[4] = {0.f, 0.f, 0.f, 0.f}, cq[4] = {0.f, 0.f, 0.f, 0.f};
    #pragma unroll
    for (int m = 0; m < 4; ++m)
        #pragma unroll
        for (int n = 0; n < 4; ++n)
            #pragma unroll
            for (int j = 0; j < 4; ++j) {
                float v = acc[m][n][j] + bias[n];
                y0bf[(size_t)(rowE + m * 16 + j) * O0 + colw + n * 16] = f2bf(v);
                cs[n] += v; cq[n] += v * v;
            }

    #pragma unroll
    for (int n = 0; n < 4; ++n) {
        float s = cs[n], qv = cq[n];
        s  += __shfl_xor(s, 16);  s  += __shfl_xor(s, 32);
        qv += __shfl_xor(qv, 16); qv += __shfl_xor(qv, 32);
        if (lane < 16) {
            atomicAdd(&sum0[colw + n * 16], s);
            atomicAdd(&sq0[colw + n * 16], qv);
        }
    }
}

// ---------------------------------------------------------------------------
// stats: scale = g * rsqrt(var+eps), shift = beta - mean*scale. UNCHANGED.
// ---------------------------------------------------------------------------
__global__ void stats_kernel(const float* __restrict__ sum, const float* __restrict__ sq,
                             const float* __restrict__ g, const float* __restrict__ beta,
                             float* __restrict__ scale, float* __restrict__ shift,
                             int C, float invM)
{
    int c = blockIdx.x * blockDim.x + threadIdx.x;
    if (c < C) {
        float mean = sum[c] * invM;
        float var  = sq[c] * invM - mean * mean;
        float s = g[c] * rsqrtf(var + 1e-5f);
        scale[c] = s;
        shift[c] = beta[c] - mean * s;
    }
}

// ---------------------------------------------------------------------------
// GEMM1 (MFMA bf16), dbuf, fused BN0+ReLU on A; y1 bf16 + BN1 stats. (r9)
// ---------------------------------------------------------------------------
__global__ __launch_bounds__(256, 2) void gemm1_mfma(
    const unsigned short* __restrict__ x1, const unsigned short* __restrict__ w1bf,
    const float* __restrict__ scale0, const float* __restrict__ shift0,
    const float* __restrict__ b1, unsigned short* __restrict__ y1bf,
    float* __restrict__ sum1, float* __restrict__ sq1)
{
    __shared__ __align__(16) unsigned short As[2][128 * 32];
    __shared__ __align__(16) unsigned short Bs[2][128 * 32];
    __shared__ float sc[O0], sh[O0];

    const int t    = threadIdx.x;
    const int lane = t & 63;
    const int w    = t >> 6;
    const int wm   = w >> 1, wn = w & 1;
    const int rowBase = blockIdx.x * 128;

    sc[t] = scale0[t];
    sh[t] = shift0[t];
    __syncthreads();

    const int r      = t >> 2;
    const int kl     = t & 3;
    const int kp     = kl ^ ((r >> 1) & 3);
    const int ks_log = kl ^ ((r >> 1) & 3);

    const unsigned short* gA0 = x1 + (size_t)(rowBase + r) * O0 + kl * 8;
    const unsigned short* gA1 = x1 + (size_t)(rowBase + 64 + r) * O0 + kl * 8;
    const unsigned short* gB0 = w1bf + (size_t)r * O0 + ks_log * 8;
    const unsigned short* gB1 = w1bf + (size_t)(64 + r) * O0 + ks_log * 8;

    const int rp = (lane & 15) * 64 + (((lane >> 4) ^ ((lane >> 1) & 3)) * 16);

    f32x4 acc[4][4] = {};

    auto stage = [&](int buf, int kt) {
        gload_lds16(gB0 + kt * 32, (char*)Bs[buf] + w * 1024);
        gload_lds16(gB1 + kt * 32, (char*)Bs[buf] + 4096 + w * 1024);

        const int ch = kt * 32 + kl * 8;
        float4 s0v = *(const float4*)(sc + ch);
        float4 s1v = *(const float4*)(sc + ch + 4);
        float4 h0v = *(const float4*)(sh + ch);
        float4 h1v = *(const float4*)(sh + ch + 4);
        short8v v0 = *(const short8v*)(gA0 + kt * 32);
        short8v v1 = *(const short8v*)(gA1 + kt * 32);
        short8v o0, o1;
        o0[0] = (short)f2bf(fmaxf(0.f, bf2f((unsigned short)v0[0]) * s0v.x + h0v.x));
        o0[1] = (short)f2bf(fmaxf(0.f, bf2f((unsigned short)v0[1]) * s0v.y + h0v.y));
        o0[2] = (short)f2bf(fmaxf(0.f, bf2f((unsigned short)v0[2]) * s0v.z + h0v.z));
        o0[3] = (short)f2bf(fmaxf(0.f, bf2f((unsigned short)v0[3]) * s0v.w + h0v.w));
        o0[4] = (short)f2bf(fmaxf(0.f, bf2f((unsigned short)v0[4]) * s1v.x + h1v.x));
        o0[5] = (short)f2bf(fmaxf(0.f, bf2f((unsigned short)v0[5]) * s1v.y + h1v.y));
        o0[6] = (short)f2bf(fmaxf(0.f, bf2f((unsigned short)v0[6]) * s1v.z + h1v.z));
        o0[7] = (short)f2bf(fmaxf(0.f, bf2f((unsigned short)v0[7]) * s1v.w + h1v.w));
        o1[0] = (short)f2bf(fmaxf(0.f, bf2f((unsigned short)v1[0]) * s0v.x + h0v.x));
        o1[1] = (short)f2bf(fmaxf(0.f, bf2f((unsigned short)v1[1]) * s0v.y + h0v.y));
        o1[2] = (short)f2bf(fmaxf(0.f, bf2f((unsigned short)v1[2]) * s0v.z + h0v.z));
        o1[3] = (short)f2bf(fmaxf(0.f, bf2f((unsigned short)v1[3]) * s0v.w + h0v.w));
        o1[4] = (short)f2bf(fmaxf(0.f, bf2f((unsigned short)v1[4]) * s1v.x + h1v.x));
        o1[5] = (short)f2bf(fmaxf(0.f, bf2f((unsigned short)v1[5]) * s1v.y + h1v.y));
        o1[6] = (short)f2bf(fmaxf(0.f, bf2f((unsigned short)v1[6]) * s1v.z + h1v.z));
        o1[7] = (short)f2bf(fmaxf(0.f, bf2f((unsigned short)v1[7]) * s1v.w + h1v.w));
        *(short8v*)(As[buf] + r * 32 + kp * 8) = o0;
        *(short8v*)(As[buf] + (64 + r) * 32 + kp * 8) = o1;
    };

    auto compute = [&](int buf) {
        const char* aB = (const char*)As[buf] + (wm * 64) * 64 + rp;
        const char* bB = (const char*)Bs[buf] + (wn * 64) * 64 + rp;
        short8v a[4], bv[4];
        #pragma unroll
        for (int m = 0; m < 4; ++m) a[m]  = *(const short8v*)(aB + m * 1024);
        #pragma unroll
        for (int n = 0; n < 4; ++n) bv[n] = *(const short8v*)(bB + n * 1024);
        #pragma unroll
        for (int m = 0; m < 4; ++m)
            #pragma unroll
            for (int n = 0; n < 4; ++n)
                acc[m][n] = __builtin_amdgcn_mfma_f32_16x16x32_bf16(
                    a[m], bv[n], acc[m][n], 0, 0, 0);
    };

    stage(0, 0);
    __syncthreads();
    #pragma unroll
    for (int kt = 0; kt < O0 / 32; ++kt) {
        if (kt + 1 < O0 / 32) stage((kt + 1) & 1, kt + 1);
        compute(kt & 1);
        __syncthreads();
    }

    const int colw = wn * 64 + (lane & 15);
    const int rowE = rowBase + wm * 64 + ((lane >> 4) * 4);
    float bias[4];
    #pragma unroll
    for (int n = 0; n < 4; ++n) bias[n] = b1[colw + n * 16];

    float cs[4] = {0.f, 0.f, 0.f, 0.f}, cq[4] = {0.f, 0.f, 0.f, 0.f};
    #pragma unroll
    for (int m = 0; m < 4; ++m)
        #pragma unroll
        for (int n = 0; n < 4; ++n)
            #pragma unroll
            for (int j = 0; j < 4; ++j) {
                float v = acc[m][n][j] + bias[n];
                y1bf[(size_t)(rowE + m * 16 + j) * O1 + colw + n * 16] = f2bf(v);
                cs[n] += v; cq[n] += v * v;
            }

    #pragma unroll
    for (int n = 0; n < 4; ++n) {
        float s = cs[n], qv = cq[n];
        s  += __shfl_xor(s, 16);  s  += __shfl_xor(s, 32);
        qv += __shfl_xor(qv, 16); qv += __shfl_xor(qv, 32);
        if (lane < 16) {
            atomicAdd(&sum1[colw + n * 16], s);
            atomicAdd(&sq1[colw + n * 16], qv);
        }
    }
}

// ---------------------------------------------------------------------------
// Final BN1 + ReLU: reads bf16 y1, writes fp32 d_out. UNCHANGED.
// ---------------------------------------------------------------------------
__global__ __launch_bounds__(256) void bn_relu_out(
    const unsigned short* __restrict__ y1bf, float* __restrict__ out,
    const float* __restrict__ scale, const float* __restrict__ shift)
{
    int i = blockIdx.x * 256 + threadIdx.x;       // chunk of 8 elems
    short8v v = ((const short8v*)y1bf)[i];
    int c = (i * 8) & (O1 - 1);
    float4 sa = *(const float4*)(scale + c);
    float4 sb = *(const float4*)(scale + c + 4);
    float4 ha = *(const float4*)(shift + c);
    float4 hb = *(const float4*)(shift + c + 4);
    float4 o0, o1;
    o0.x = fmaxf(0.f, bf2f((unsigned short)v[0]) * sa.x + ha.x);
    o0.y = fmaxf(0.f, bf2f((unsigned short)v[1]) * sa.y + ha.y);
    o0.z = fmaxf(0.f, bf2f((unsigned short)v[2]) * sa.z + ha.z);
    o0.w = fmaxf(0.f, bf2f((unsigned short)v[3]) * sa.w + ha.w);
    o1.x = fmaxf(0.f, bf2f((unsigned short)v[4]) * sb.x + hb.x);
    o1.y = fmaxf(0.f, bf2f((unsigned short)v[5]) * sb.y + hb.y);
    o1.z = fmaxf(0.f, bf2f((unsigned short)v[6]) * sb.z + hb.z);
    o1.w = fmaxf(0.f, bf2f((unsigned short)v[7]) * sb.w + hb.w);
    ((float4*)out)[i * 2 + 0] = o0;
    ((float4*)out)[i * 2 + 1] = o1;
}

// ---------------------------------------------------------------------------
// ws layout (float offsets), peak 16844288 f = 67.4 MB:
//   0..1536        stats
//   1536..50688    w0bf
//   50688..67072   w1bf
//   OVERLAY @67072 (all dead before gemm0 writes y0bf here):
//     candP @132608..3278336   (24 x M u64; dead after nn3_merge)
//     idx3  @3278336..3474944  (dead after interp)
//     wgt3  @3474944..3671552  (dead after interp)
//   y0bf @67072..8455680       (written by gemm0)
//   xI   @8455680..16844288    (dead after gemm0; y1bf overlays it)
//   y1bf @8455680..12649984    (written by gemm1)
// ---------------------------------------------------------------------------
extern "C" void kernel_launch(void* const* d_in, const int* in_sizes, int n_in,
                              void* d_out, int out_size, void* d_ws, size_t ws_size,
                              hipStream_t stream)
{
    const float* xyz1    = (const float*)d_in[0];
    const float* xyz2    = (const float*)d_in[1];
    const float* points1 = (const float*)d_in[2];
    const float* points2 = (const float*)d_in[3];
    const float* w0      = (const float*)d_in[4];
    const float* b0      = (const float*)d_in[5];
    const float* g0      = (const float*)d_in[6];
    const float* beta0   = (const float*)d_in[7];
    const float* w1      = (const float*)d_in[8];
    const float* b1      = (const float*)d_in[9];
    const float* g1      = (const float*)d_in[10];
    const float* beta1   = (const float*)d_in[11];

    float* wsf = (float*)d_ws;
    float* sum0   = wsf;
    float* sq0    = wsf + 256;
    float* sum1   = wsf + 512;
    float* sq1    = wsf + 640;
    float* scale0 = wsf + 768;
    float* shift0 = wsf + 1024;
    float* scale1 = wsf + 1280;
    float* shift1 = wsf + 1408;
    unsigned short* w0bf = (unsigned short*)(wsf + 1536);
    unsigned short* w1bf = (unsigned short*)(wsf + 50688);
    u64*    candP = (u64*)(wsf + 132608);
    int*    idx3  = (int*)(wsf + 3278336);
    float*  wgt3  = wsf + 3474944;
    unsigned short* y0bf = (unsigned short*)(wsf + 67072);
    unsigned short* xI   = (unsigned short*)(wsf + 8455680);
    unsigned short* y1bf = (unsigned short*)(wsf + 8455680);

    hipMemsetAsync(d_ws, 0, 768 * sizeof(float), stream);

    cvt_weights<<<(O0 * C_IN / 4 + O1 * O0 / 4) / 256, 256, 0, stream>>>(
        w0, w1, w0bf, w1bf);

    nn3_scan<<<dim3(MROWS / 256, NCHUNK), 256, 0, stream>>>(xyz1, xyz2, candP);
    nn3_merge<<<MROWS / 256, 256, 0, stream>>>(candP, idx3, wgt3);

    interp_kernel<<<MROWS / 4, 256, 0, stream>>>(points2, idx3, wgt3, xI);

    gemm0_mfma<<<MROWS / 128, 512, 0, stream>>>(
        points1, xI, w0bf, b0, y0bf, sum0, sq0);

    stats_kernel<<<1, 256, 0, stream>>>(sum0, sq0, g0, beta0, scale0, shift0,
                                        O0, 1.0f / MROWS);

    gemm1_mfma<<<MROWS / 128, 256, 0, stream>>>(
        y0bf, w1bf, scale0, shift0, b1, y1bf, sum1, sq1);

    stats_kernel<<<1, 128, 0, stream>>>(sum1, sq1, g1, beta1, scale1, shift1,
                                        O1, 1.0f / MROWS);

    bn_relu_out<<<(MROWS * O1 / 8) / 256, 256, 0, stream>>>(
        y1bf, (float*)d_out, scale1, shift1);
}